// Round 4
// baseline (720.206 us; speedup 1.0000x reference)
//
#include <hip/hip_runtime.h>
#include <hip/hip_bf16.h>
#include <math.h>

#define NEG_SLOPE 0.2f

// ---------------------------------------------------------------------------
// K1: h = x @ W + b_W (kept in registers), emit:
//   hb  [N][64] uint  : {bf16 h(head0,d), bf16 h(head1,d)} interleaved
//   ai  [N][2]        : dot(att_i[hh], h[n,hh])   (x_i logit term)
//   ajs [N] float4    : {aj0, aj1, 0, 0} — z/w become softmax denoms later
// block = 128 threads (2 waves); wave == head.
// ---------------------------------------------------------------------------
__global__ __launch_bounds__(128) void k1_gemm(
    const float* __restrict__ x, const float* __restrict__ W,
    const float* __restrict__ bW, const float* __restrict__ att,
    unsigned int* __restrict__ hb, float* __restrict__ ai,
    float* __restrict__ ajs, int Nn) {
  __shared__ float Ws[64 * 128];
  __shared__ float xs[64];
  __shared__ float bs[128];
  __shared__ float atts[256];
  int t = threadIdx.x;  // 0..127
  for (int i = t; i < 64 * 128; i += 128) Ws[i] = W[i];
  bs[t] = bW[t];
  atts[t] = att[t];
  atts[128 + t] = att[128 + t];
  __syncthreads();
  int head = t >> 6;
  int lane = t & 63;
  unsigned short* hbs = (unsigned short*)hb;
  for (int row = blockIdx.x; row < Nn; row += gridDim.x) {
    if (t < 64) xs[t] = x[(size_t)row * 64 + t];
    __syncthreads();
    float acc = bs[t];
#pragma unroll
    for (int k = 0; k < 64; ++k) acc += xs[k] * Ws[k * 128 + t];
    // bf16 round-to-nearest-even, interleaved store
    unsigned u = __float_as_uint(acc);
    unsigned short us = (unsigned short)((u + 0x7fffu + ((u >> 16) & 1u)) >> 16);
    hbs[(size_t)row * 128 + lane * 2 + head] = us;
    float ti = atts[head * 128 + lane] * acc;        // x_i coefficient
    float tj = atts[head * 128 + 64 + lane] * acc;   // x_j coefficient
#pragma unroll
    for (int off = 32; off > 0; off >>= 1) {
      ti += __shfl_down(ti, off, 64);
      tj += __shfl_down(tj, off, 64);
    }
    if (lane == 0) {
      ai[row * 2 + head] = ti;
      ajs[row * 4 + head] = tj;   // .x / .y ; .z/.w stay 0 from memset
    }
    __syncthreads();
  }
}

// ---------------------------------------------------------------------------
// CSR build by DESTINATION: histogram -> exclusive scan -> fill.
// ---------------------------------------------------------------------------
__global__ __launch_bounds__(256) void k_deg(
    const int* __restrict__ ei, int* __restrict__ deg, int Ee) {
  int e = blockIdx.x * blockDim.x + threadIdx.x;
  if (e < Ee) atomicAdd(&deg[ei[Ee + e]], 1);
}

__global__ __launch_bounds__(256) void k_scan1(
    const int* __restrict__ deg, int* __restrict__ off, int* __restrict__ bsum, int Nn) {
  __shared__ int s[256];
  int t = threadIdx.x;
  int i = blockIdx.x * 256 + t;
  int v = (i < Nn) ? deg[i] : 0;
  s[t] = v;
  __syncthreads();
#pragma unroll
  for (int o = 1; o < 256; o <<= 1) {
    int xv = (t >= o) ? s[t - o] : 0;
    __syncthreads();
    s[t] += xv;
    __syncthreads();
  }
  if (i < Nn) off[i] = s[t] - v;
  if (t == 255) bsum[blockIdx.x] = s[t];
}

__global__ __launch_bounds__(256) void k_scan2(
    int* __restrict__ bsum, int* __restrict__ bpre, int nb) {
  __shared__ int s[256];
  int t = threadIdx.x;
  int v = (t < nb) ? bsum[t] : 0;
  s[t] = v;
  __syncthreads();
#pragma unroll
  for (int o = 1; o < 256; o <<= 1) {
    int xv = (t >= o) ? s[t - o] : 0;
    __syncthreads();
    s[t] += xv;
    __syncthreads();
  }
  if (t < nb) bpre[t] = s[t] - v;
}

__global__ __launch_bounds__(256) void k_scan3(
    int* __restrict__ off, const int* __restrict__ bpre, int Nn, int Ee) {
  int i = blockIdx.x * 256 + threadIdx.x;
  if (i < Nn) off[i] += bpre[blockIdx.x];
  if (i == 0) off[Nn] = Ee;
}

// ---------------------------------------------------------------------------
// K_fill: per-edge ea = exp(leaky(logit)); accumulate softmax denominators
// into ajs[src].z/.w; scatter ONE 4-byte word per edge:
//   eix[pos] = edge_id (21b) | a0<<21 | a1<<24 | a2<<27
// ---------------------------------------------------------------------------
__global__ __launch_bounds__(256) void k_fill(
    const int* __restrict__ ei, const int* __restrict__ eattr,
    const float* __restrict__ att, const float* __restrict__ bemb,
    const float* __restrict__ ai, float* __restrict__ ajs,
    const int* __restrict__ off, int* __restrict__ wcur,
    unsigned int* __restrict__ eix, int Ee) {
  __shared__ float tbl[30];  // [f][c][hh] = f*10 + c*2 + hh
  int t = threadIdx.x;
  if (t < 30) {
    int f = t / 10, rem = t % 10, c = rem >> 1, hh = rem & 1;
    float sacc = 0.f;
    for (int d = 0; d < 64; ++d)
      sacc += att[hh * 128 + 64 + d] * bemb[(f * 5 + c) * 128 + hh * 64 + d];
    tbl[t] = sacc;
  }
  __syncthreads();
  int e = blockIdx.x * blockDim.x + t;
  if (e >= Ee) return;
  int r = ei[e], c = ei[Ee + e];
  int a0 = eattr[e * 3], a1 = eattr[e * 3 + 1], a2 = eattr[e * 3 + 2];
  float aj0 = ajs[r * 4], aj1 = ajs[r * 4 + 1];
  float ai0 = ai[c * 2], ai1 = ai[c * 2 + 1];
  float lg0 = ai0 + aj0 + tbl[a0 * 2] + tbl[10 + a1 * 2] + tbl[20 + a2 * 2];
  float lg1 = ai1 + aj1 + tbl[a0 * 2 + 1] + tbl[10 + a1 * 2 + 1] + tbl[20 + a2 * 2 + 1];
  lg0 = lg0 >= 0.f ? lg0 : NEG_SLOPE * lg0;
  lg1 = lg1 >= 0.f ? lg1 : NEG_SLOPE * lg1;
  atomicAdd(&ajs[r * 4 + 2], __expf(lg0));
  atomicAdd(&ajs[r * 4 + 3], __expf(lg1));
  int pos = off[c] + atomicAdd(&wcur[c], 1);
  eix[pos] = (unsigned)e | ((unsigned)a0 << 21) | ((unsigned)a1 << 24) |
             ((unsigned)a2 << 27);
}

// ---------------------------------------------------------------------------
// K_gather: one wave per dst node, lane = d. Recomputes ea from the packed
// attrs + per-node scalars (VALU is idle), reads bf16 h (256B/edge), zero
// atomics, fused head-mean + bias.
// ---------------------------------------------------------------------------
__global__ __launch_bounds__(256) void k_gather(
    const unsigned int* __restrict__ eix, const int* __restrict__ off,
    const int* __restrict__ ei, const float4* __restrict__ ajs,
    const float* __restrict__ ai, const unsigned int* __restrict__ hb,
    const float* __restrict__ bemb, const float* __restrict__ att,
    const float* __restrict__ bias, float* __restrict__ out, int Nn) {
  __shared__ float bembs[3 * 5 * 128];
  __shared__ float tbl[30];
  int t = threadIdx.x;
  if (t < 30) {
    int f = t / 10, rem = t % 10, c = rem >> 1, hh = rem & 1;
    float sacc = 0.f;
    for (int d = 0; d < 64; ++d)
      sacc += att[hh * 128 + 64 + d] * bemb[(f * 5 + c) * 128 + hh * 64 + d];
    tbl[t] = sacc;
  }
  for (int i = t; i < 3 * 5 * 128; i += 256) bembs[i] = bemb[i];
  __syncthreads();
  int wave = t >> 6;
  int lane = t & 63;
  int n = blockIdx.x * 4 + wave;
  if (n >= Nn) return;
  int p0 = off[n], p1 = off[n + 1];
  float ai0 = ai[n * 2], ai1 = ai[n * 2 + 1];
  float acc0 = 0.f, acc1 = 0.f;
  unsigned pk = 0; int r = 0;
  if (p0 < p1) { pk = eix[p0]; r = ei[pk & 0x1FFFFFu]; }
  for (int p = p0; p < p1; ++p) {
    unsigned pk_c = pk; int r_c = r;
    if (p + 1 < p1) { pk = eix[p + 1]; r = ei[pk & 0x1FFFFFu]; }
    float4 aw = ajs[r_c];                              // {aj0,aj1,s0,s1}
    unsigned hv = hb[(size_t)r_c * 64 + lane];         // bf16x2 gather
    int a0 = (pk_c >> 21) & 7, a1 = (pk_c >> 24) & 7, a2 = (pk_c >> 27) & 7;
    float lg0 = ai0 + aw.x + tbl[a0 * 2] + tbl[10 + a1 * 2] + tbl[20 + a2 * 2];
    float lg1 = ai1 + aw.y + tbl[a0 * 2 + 1] + tbl[10 + a1 * 2 + 1] + tbl[20 + a2 * 2 + 1];
    lg0 = lg0 >= 0.f ? lg0 : NEG_SLOPE * lg0;
    lg1 = lg1 >= 0.f ? lg1 : NEG_SLOPE * lg1;
    float al0 = __expf(lg0) / (aw.z + 1e-16f);
    float al1 = __expf(lg1) / (aw.w + 1e-16f);
    float h0 = __uint_as_float(hv << 16);
    float h1 = __uint_as_float(hv & 0xffff0000u);
    int b0 = a0 * 128, b1 = a1 * 128 + 640, b2 = a2 * 128 + 1280;
    float e0 = bembs[b0 + lane] + bembs[b1 + lane] + bembs[b2 + lane];
    float e1 = bembs[b0 + 64 + lane] + bembs[b1 + 64 + lane] + bembs[b2 + 64 + lane];
    acc0 += al0 * (h0 + e0);
    acc1 += al1 * (h1 + e1);
  }
  out[(size_t)n * 64 + lane] = 0.5f * (acc0 + acc1) + bias[lane];
}

extern "C" void kernel_launch(void* const* d_in, const int* in_sizes, int n_in,
                              void* d_out, int out_size, void* d_ws, size_t ws_size,
                              hipStream_t stream) {
  const float* x    = (const float*)d_in[0];
  const int*   ei   = (const int*)d_in[1];
  const int*   eatt = (const int*)d_in[2];
  const float* W    = (const float*)d_in[3];
  const float* bW   = (const float*)d_in[4];
  const float* att  = (const float*)d_in[5];
  const float* bias = (const float*)d_in[6];
  const float* bemb = (const float*)d_in[7];
  int Nn = in_sizes[0] / 64;
  int Ee = in_sizes[1] / 2;
  int nb1 = (Nn + 255) / 256;

  char* ws = (char*)d_ws;
  ws = (char*)(((uintptr_t)ws + 15) & ~(uintptr_t)15);
  float* ajs = (float*)ws;         ws += (size_t)Nn * 4 * 4;   // {aj0,aj1,s0,s1}
  float* ai = (float*)ws;          ws += (size_t)Nn * 2 * 4;
  unsigned int* hb = (unsigned int*)ws; ws += (size_t)Nn * 64 * 4;
  int* deg = (int*)ws;             ws += (size_t)Nn * 4;
  int* wcur = (int*)ws;            ws += (size_t)Nn * 4;
  int* off = (int*)ws;             ws += (size_t)(Nn + 1) * 4;
  int* bsum = (int*)ws;            ws += (size_t)nb1 * 4;
  int* bpre = (int*)ws;            ws += (size_t)nb1 * 4;
  unsigned int* eix = (unsigned int*)ws; ws += (size_t)Ee * 4;

  hipMemsetAsync(ajs, 0, (size_t)Nn * 4 * 4, stream);
  hipMemsetAsync(deg, 0, (size_t)Nn * 4, stream);
  hipMemsetAsync(wcur, 0, (size_t)Nn * 4, stream);

  k1_gemm<<<1024, 128, 0, stream>>>(x, W, bW, att, hb, ai, ajs, Nn);
  k_deg<<<(Ee + 255) / 256, 256, 0, stream>>>(ei, deg, Ee);
  k_scan1<<<nb1, 256, 0, stream>>>(deg, off, bsum, Nn);
  k_scan2<<<1, 256, 0, stream>>>(bsum, bpre, nb1);
  k_scan3<<<nb1, 256, 0, stream>>>(off, bpre, Nn, Ee);
  k_fill<<<(Ee + 255) / 256, 256, 0, stream>>>(ei, eatt, att, bemb, ai, ajs,
                                               off, wcur, eix, Ee);
  k_gather<<<(Nn + 3) / 4, 256, 0, stream>>>(eix, off, ei, (const float4*)ajs,
                                             ai, hb, bemb, att, bias,
                                             (float*)d_out, Nn);
}

// Round 5
// 682.008 us; speedup vs baseline: 1.0560x; 1.0560x over previous
//
#include <hip/hip_runtime.h>
#include <hip/hip_bf16.h>
#include <math.h>

#define NEG_SLOPE 0.2f

__device__ __forceinline__ unsigned f2bf(float f) {
  unsigned u = __float_as_uint(f);
  return (u + 0x7fffu + ((u >> 16) & 1u)) >> 16;  // RNE
}

// ---------------------------------------------------------------------------
// K1: h = x @ W + b_W (registers), emit:
//   hb  [N][64] uint : {bf16 h(head0,d) lo | bf16 h(head1,d) hi}
//   ai  [N][2]       : dot(att_i[hh], h[n,hh])
//   aj  [N][2]       : dot(att_j[hh], h[n,hh])
// block = 128 threads (2 waves); wave == head for reductions.
// ---------------------------------------------------------------------------
__global__ __launch_bounds__(128) void k1_gemm(
    const float* __restrict__ x, const float* __restrict__ W,
    const float* __restrict__ bW, const float* __restrict__ att,
    unsigned int* __restrict__ hb, float* __restrict__ ai,
    float* __restrict__ aj, int Nn) {
  __shared__ float Ws[64 * 128];
  __shared__ float xs[64];
  __shared__ float bs[128];
  __shared__ float atts[256];
  __shared__ float hsh[128];
  int t = threadIdx.x;  // 0..127
  for (int i = t; i < 64 * 128; i += 128) Ws[i] = W[i];
  bs[t] = bW[t];
  atts[t] = att[t];
  atts[128 + t] = att[128 + t];
  __syncthreads();
  int head = t >> 6;
  int lane = t & 63;
  for (int row = blockIdx.x; row < Nn; row += gridDim.x) {
    if (t < 64) xs[t] = x[(size_t)row * 64 + t];
    __syncthreads();
    float acc = bs[t];
#pragma unroll
    for (int k = 0; k < 64; ++k) acc += xs[k] * Ws[k * 128 + t];
    hsh[t] = acc;
    float ti = atts[head * 128 + lane] * acc;        // x_i coefficient
    float tj = atts[head * 128 + 64 + lane] * acc;   // x_j coefficient
#pragma unroll
    for (int off = 32; off > 0; off >>= 1) {
      ti += __shfl_down(ti, off, 64);
      tj += __shfl_down(tj, off, 64);
    }
    if (lane == 0) { ai[row * 2 + head] = ti; aj[row * 2 + head] = tj; }
    __syncthreads();
    if (t < 64)  // coalesced packed store: one dword per lane
      hb[(size_t)row * 64 + t] = f2bf(hsh[t]) | (f2bf(hsh[64 + t]) << 16);
  }
}

// ---------------------------------------------------------------------------
// CSR build by DESTINATION: histogram -> exclusive scan -> fill.
// ---------------------------------------------------------------------------
__global__ __launch_bounds__(256) void k_deg(
    const int* __restrict__ ei, int* __restrict__ deg, int Ee) {
  int e = blockIdx.x * blockDim.x + threadIdx.x;
  if (e < Ee) atomicAdd(&deg[ei[Ee + e]], 1);
}

__global__ __launch_bounds__(256) void k_scan1(
    const int* __restrict__ deg, int* __restrict__ off, int* __restrict__ bsum, int Nn) {
  __shared__ int s[256];
  int t = threadIdx.x;
  int i = blockIdx.x * 256 + t;
  int v = (i < Nn) ? deg[i] : 0;
  s[t] = v;
  __syncthreads();
#pragma unroll
  for (int o = 1; o < 256; o <<= 1) {
    int xv = (t >= o) ? s[t - o] : 0;
    __syncthreads();
    s[t] += xv;
    __syncthreads();
  }
  if (i < Nn) off[i] = s[t] - v;
  if (t == 255) bsum[blockIdx.x] = s[t];
}

__global__ __launch_bounds__(256) void k_scan2(
    int* __restrict__ bsum, int* __restrict__ bpre, int nb) {
  __shared__ int s[256];
  int t = threadIdx.x;
  int v = (t < nb) ? bsum[t] : 0;
  s[t] = v;
  __syncthreads();
#pragma unroll
  for (int o = 1; o < 256; o <<= 1) {
    int xv = (t >= o) ? s[t - o] : 0;
    __syncthreads();
    s[t] += xv;
    __syncthreads();
  }
  if (t < nb) bpre[t] = s[t] - v;
}

__global__ __launch_bounds__(256) void k_scan3(
    int* __restrict__ off, const int* __restrict__ bpre, int Nn, int Ee) {
  int i = blockIdx.x * 256 + threadIdx.x;
  if (i < Nn) off[i] += bpre[blockIdx.x];
  if (i == 0) off[Nn] = Ee;
}

// ---------------------------------------------------------------------------
// K_fill: softmax denominators (atomic, separate array from read-only aj) +
// 4-byte CSR record scatter: {src:17b | a0<<17 | a1<<20 | a2<<23}.
// ---------------------------------------------------------------------------
__global__ __launch_bounds__(256) void k_fill(
    const int* __restrict__ ei, const int* __restrict__ eattr,
    const float* __restrict__ att, const float* __restrict__ bemb,
    const float* __restrict__ ai, const float* __restrict__ aj,
    float* __restrict__ sden, const int* __restrict__ off,
    int* __restrict__ wcur, unsigned int* __restrict__ eix, int Ee) {
  __shared__ float tbl[30];  // [f][c][hh] = f*10 + c*2 + hh
  int t = threadIdx.x;
  if (t < 30) {
    int f = t / 10, rem = t % 10, c = rem >> 1, hh = rem & 1;
    float sacc = 0.f;
    for (int d = 0; d < 64; ++d)
      sacc += att[hh * 128 + 64 + d] * bemb[(f * 5 + c) * 128 + hh * 64 + d];
    tbl[t] = sacc;
  }
  __syncthreads();
  int e = blockIdx.x * blockDim.x + t;
  if (e >= Ee) return;
  int r = ei[e], c = ei[Ee + e];
  int a0 = eattr[e * 3], a1 = eattr[e * 3 + 1], a2 = eattr[e * 3 + 2];
  float lg0 = ai[c * 2] + aj[r * 2] + tbl[a0 * 2] + tbl[10 + a1 * 2] + tbl[20 + a2 * 2];
  float lg1 = ai[c * 2 + 1] + aj[r * 2 + 1] + tbl[a0 * 2 + 1] + tbl[10 + a1 * 2 + 1] +
              tbl[20 + a2 * 2 + 1];
  lg0 = lg0 >= 0.f ? lg0 : NEG_SLOPE * lg0;
  lg1 = lg1 >= 0.f ? lg1 : NEG_SLOPE * lg1;
  atomicAdd(&sden[r * 2], __expf(lg0));
  atomicAdd(&sden[r * 2 + 1], __expf(lg1));
  int pos = off[c] + atomicAdd(&wcur[c], 1);
  unsigned rec = (unsigned)r | ((unsigned)a0 << 17) | ((unsigned)a1 << 20) |
                 ((unsigned)a2 << 23);
  __builtin_nontemporal_store(rec, &eix[pos]);
}

// ---------------------------------------------------------------------------
// K_gather: one wave per dst node, lane = d; 4-way unrolled edge loop with
// batched independent loads (4 hb gathers + 4 aj + 4 sden in flight).
// Edge-emb via pair-combined LDS table (4 LDS reads/edge instead of 6).
// ---------------------------------------------------------------------------
__global__ __launch_bounds__(256) void k_gather(
    const unsigned int* __restrict__ eix, const int* __restrict__ off,
    const float2* __restrict__ aj2, const float2* __restrict__ sd2,
    const float* __restrict__ ai, const unsigned int* __restrict__ hb,
    const float* __restrict__ bemb, const float* __restrict__ att,
    const float* __restrict__ bias, float* __restrict__ out, int Nn) {
  __shared__ float t01s[25 * 128];  // bemb0[a0]+bemb1[a1] pair table
  __shared__ float b2s[5 * 128];
  __shared__ float tbl[30];
  int t = threadIdx.x;
  if (t < 30) {
    int f = t / 10, rem = t % 10, c = rem >> 1, hh = rem & 1;
    float sacc = 0.f;
    for (int d = 0; d < 64; ++d)
      sacc += att[hh * 128 + 64 + d] * bemb[(f * 5 + c) * 128 + hh * 64 + d];
    tbl[t] = sacc;
  }
  for (int i = t; i < 25 * 128; i += 256) {
    int c01 = i >> 7, d = i & 127;
    t01s[i] = bemb[(c01 / 5) * 128 + d] + bemb[640 + (c01 % 5) * 128 + d];
  }
  for (int i = t; i < 5 * 128; i += 256) b2s[i] = bemb[1280 + i];
  __syncthreads();
  int wave = t >> 6;
  int lane = t & 63;
  int n = blockIdx.x * 4 + wave;
  if (n >= Nn) return;
  int p0 = off[n], p1 = off[n + 1];
  float ai0 = ai[n * 2], ai1 = ai[n * 2 + 1];
  float acc0 = 0.f, acc1 = 0.f;

#define EDGE_BODY(U, HV, AJV, SDV)                                             \
  {                                                                            \
    int a0 = (U >> 17) & 7, a1 = (U >> 20) & 7, a2 = (U >> 23) & 7;            \
    float lg0 = ai0 + AJV.x + tbl[a0 * 2] + tbl[10 + a1 * 2] + tbl[20 + a2 * 2]; \
    float lg1 = ai1 + AJV.y + tbl[a0 * 2 + 1] + tbl[10 + a1 * 2 + 1] +         \
                tbl[20 + a2 * 2 + 1];                                          \
    lg0 = lg0 >= 0.f ? lg0 : NEG_SLOPE * lg0;                                  \
    lg1 = lg1 >= 0.f ? lg1 : NEG_SLOPE * lg1;                                  \
    float al0 = __expf(lg0) / (SDV.x + 1e-16f);                                \
    float al1 = __expf(lg1) / (SDV.y + 1e-16f);                                \
    int bp = (a0 * 5 + a1) * 128, b2 = a2 * 128;                               \
    float e0 = t01s[bp + lane] + b2s[b2 + lane];                               \
    float e1 = t01s[bp + 64 + lane] + b2s[b2 + 64 + lane];                     \
    acc0 += al0 * (__uint_as_float(HV << 16) + e0);                            \
    acc1 += al1 * (__uint_as_float(HV & 0xffff0000u) + e1);                    \
  }

  int p = p0;
  for (; p + 4 <= p1; p += 4) {
    unsigned u0 = eix[p], u1 = eix[p + 1], u2 = eix[p + 2], u3 = eix[p + 3];
    int r0 = u0 & 0x1FFFF, r1 = u1 & 0x1FFFF, r2 = u2 & 0x1FFFF, r3 = u3 & 0x1FFFF;
    unsigned hv0 = hb[(size_t)r0 * 64 + lane];
    unsigned hv1 = hb[(size_t)r1 * 64 + lane];
    unsigned hv2 = hb[(size_t)r2 * 64 + lane];
    unsigned hv3 = hb[(size_t)r3 * 64 + lane];
    float2 ajv0 = aj2[r0], ajv1 = aj2[r1], ajv2 = aj2[r2], ajv3 = aj2[r3];
    float2 sdv0 = sd2[r0], sdv1 = sd2[r1], sdv2 = sd2[r2], sdv3 = sd2[r3];
    EDGE_BODY(u0, hv0, ajv0, sdv0)
    EDGE_BODY(u1, hv1, ajv1, sdv1)
    EDGE_BODY(u2, hv2, ajv2, sdv2)
    EDGE_BODY(u3, hv3, ajv3, sdv3)
  }
  for (; p < p1; ++p) {
    unsigned u0 = eix[p];
    int r0 = u0 & 0x1FFFF;
    unsigned hv0 = hb[(size_t)r0 * 64 + lane];
    float2 ajv0 = aj2[r0];
    float2 sdv0 = sd2[r0];
    EDGE_BODY(u0, hv0, ajv0, sdv0)
  }
#undef EDGE_BODY
  out[(size_t)n * 64 + lane] = 0.5f * (acc0 + acc1) + bias[lane];
}

extern "C" void kernel_launch(void* const* d_in, const int* in_sizes, int n_in,
                              void* d_out, int out_size, void* d_ws, size_t ws_size,
                              hipStream_t stream) {
  const float* x    = (const float*)d_in[0];
  const int*   ei   = (const int*)d_in[1];
  const int*   eatt = (const int*)d_in[2];
  const float* W    = (const float*)d_in[3];
  const float* bW   = (const float*)d_in[4];
  const float* att  = (const float*)d_in[5];
  const float* bias = (const float*)d_in[6];
  const float* bemb = (const float*)d_in[7];
  int Nn = in_sizes[0] / 64;
  int Ee = in_sizes[1] / 2;
  int nb1 = (Nn + 255) / 256;

  char* ws = (char*)d_ws;
  ws = (char*)(((uintptr_t)ws + 15) & ~(uintptr_t)15);
  float* aj = (float*)ws;          ws += (size_t)Nn * 2 * 4;
  float* sden = (float*)ws;        ws += (size_t)Nn * 2 * 4;
  float* ai = (float*)ws;          ws += (size_t)Nn * 2 * 4;
  unsigned int* hb = (unsigned int*)ws; ws += (size_t)Nn * 64 * 4;
  int* deg = (int*)ws;             ws += (size_t)Nn * 4;
  int* wcur = (int*)ws;            ws += (size_t)Nn * 4;
  int* off = (int*)ws;             ws += (size_t)(Nn + 1) * 4;
  int* bsum = (int*)ws;            ws += (size_t)nb1 * 4;
  int* bpre = (int*)ws;            ws += (size_t)nb1 * 4;
  unsigned int* eix = (unsigned int*)ws; ws += (size_t)Ee * 4;

  hipMemsetAsync(sden, 0, (size_t)Nn * 2 * 4, stream);
  hipMemsetAsync(deg, 0, (size_t)Nn * 4, stream);
  hipMemsetAsync(wcur, 0, (size_t)Nn * 4, stream);

  k1_gemm<<<1024, 128, 0, stream>>>(x, W, bW, att, hb, ai, aj, Nn);
  k_deg<<<(Ee + 255) / 256, 256, 0, stream>>>(ei, deg, Ee);
  k_scan1<<<nb1, 256, 0, stream>>>(deg, off, bsum, Nn);
  k_scan2<<<1, 256, 0, stream>>>(bsum, bpre, nb1);
  k_scan3<<<nb1, 256, 0, stream>>>(off, bpre, Nn, Ee);
  k_fill<<<(Ee + 255) / 256, 256, 0, stream>>>(ei, eatt, att, bemb, ai, aj,
                                               sden, off, wcur, eix, Ee);
  k_gather<<<(Nn + 3) / 4, 256, 0, stream>>>(eix, off, (const float2*)aj,
                                             (const float2*)sden, ai, hb, bemb,
                                             att, bias, (float*)d_out, Nn);
}